// Round 1
// 326.313 us; speedup vs baseline: 1.0005x; 1.0005x over previous
//
#include <hip/hip_runtime.h>
#include <hip/hip_bf16.h>

#define M 2048
#define N 131072
#define D 256

#define SLICE_G 64                     // n-groups (of 16) per slice = 1024 n = 512 KB f16
#define NSLICE  (N / (SLICE_G * 16))   // 128
#define BIAS    1024.0f                // score = vsq+BIAS-2qv > 0 -> uint-sortable bits

typedef __attribute__((ext_vector_type(8))) _Float16 half8;  // 8 f16 (4 VGPRs)
typedef __attribute__((ext_vector_type(8))) short short8;
typedef __attribute__((ext_vector_type(4))) float f32x4;     // MFMA acc
typedef unsigned long long ull;

__device__ __forceinline__ ull pack_key(float score, unsigned idx) {
    unsigned u = __float_as_uint(score);
    u = (u & 0x80000000u) ? ~u : (u | 0x80000000u);
    return ((ull)u << 32) | idx;
}

// async 16B global -> LDS (wave-uniform LDS base; HW adds lane*16)
__device__ __forceinline__ void gload_lds16(const void* g, void* l) {
    __builtin_amdgcn_global_load_lds(
        (const __attribute__((address_space(1))) void*)g,
        (__attribute__((address_space(3))) void*)l, 16, 0, 0);
}

// ---------------- Kernel A (fused): V and Q -> f16 FRAGMENT-LINEAR, direct ----------
// Frag order IS well-coalesced from global: per wave instr, 16 rows x 128B contiguous
// segments (each lane a contiguous 32B). No LDS bounce (old path had 8-way read bank
// conflicts on the padded gather + an extra barrier).
__global__ __launch_bounds__(256) void convert_fused(const float* __restrict__ v,
                                                     const float* __restrict__ q,
                                                     short* __restrict__ vf,
                                                     short* __restrict__ qf,
                                                     float* __restrict__ vsqb,
                                                     ull* __restrict__ keys) {
    __shared__ float part[4][16];

    const int b    = blockIdx.x;
    const bool isV = (b < N / 16);
    const int g    = isV ? b : (b - N / 16);
    const float* x = isV ? v : q;
    short* xf      = isV ? vf : qf;

    const int t    = threadIdx.x;
    const int w    = t >> 6;
    const int l    = t & 63;
    const int quad = (l >> 4) & 3;
    const int tx   = l & 15;

    const float* src = x + (size_t)g * 4096;
    float s = 0.f;
#pragma unroll
    for (int h = 0; h < 2; ++h) {
        const int c = w + h * 4;
        const float* p = src + tx * 256 + c * 32 + quad * 8;   // contiguous 32B/lane
        const float4 f0 = *(const float4*)p;
        const float4 f1 = *(const float4*)(p + 4);
        float tmp[8] __attribute__((aligned(16))) = {f0.x, f0.y, f0.z, f0.w,
                                                     f1.x, f1.y, f1.z, f1.w};
        half8 hh;
#pragma unroll
        for (int e = 0; e < 8; ++e) {
            hh[e] = (_Float16)tmp[e];
            s += tmp[e] * tmp[e];
        }
        *(short8*)(xf + ((size_t)g * 8 + c) * 512 + l * 8) = *(short8*)&hh;
    }

    if (isV) {
        s += __shfl_xor(s, 16, 64);
        s += __shfl_xor(s, 32, 64);
        if (l < 16) part[w][l] = s;
        __syncthreads();
        if (t < 16) vsqb[g * 16 + t] = part[0][t] + part[1][t] + part[2][t] + part[3][t] + BIAS;
    } else if (g == 0) {
        for (int i = t; i < 2 * M; i += 256) keys[i] = ~0ull;
    }
}

// ---------------- Kernel B: 64 q-rows/wave; B-tiles staged in LDS (shared x4 waves) ----
// A-frags (4 strips x 8 chunks = 128 regs) resident. Per g, the 8KB B-tile is loaded
// ONCE per block via async global_load_lds (frag-linear global layout == linear LDS
// memcpy), double-buffered, then each wave ds_reads its frags (lane*16 linear,
// conflict-free). Cuts B global traffic 4x and frees the 64-VGPR B ping-pong; the
// 2-phase barrier pipeline gives a full compute phase (~1.2k cyc) of prefetch cover.
__global__ __launch_bounds__(256, 2) void dist_argmin_reg(const short* __restrict__ qf,
                                                          const short* __restrict__ vf,
                                                          const float* __restrict__ vsqb,
                                                          ull* __restrict__ keys1,
                                                          ull* __restrict__ keys2) {
    __shared__ short bt[2][8 * 512];       // 2 x 8KB B-tile double buffer

    const int tid  = threadIdx.x;
    const int lane = tid & 63;
    const int w    = tid >> 6;
    const int tx   = lane & 15;
    const int quad = (lane >> 4) & 3;

    // XCD swizzle: 1024 blocks; lb%8 = XCD; each XCD covers its own 16 slices (8 MB)
    const int lb    = blockIdx.x;
    const int xcd   = lb & 7;
    const int s_    = lb >> 3;              // 0..127 within XCD
    const int slice = xcd * 16 + (s_ >> 3);
    const int qblk  = s_ & 7;

    const int qb0 = qblk * 256 + w * 64;    // wave's first q-row (64 rows)
    const int sg0 = slice * SLICE_G;

    half8 aq[4][8];                         // 128 regs, loaded once
#pragma unroll
    for (int mt = 0; mt < 4; ++mt)
#pragma unroll
        for (int c = 0; c < 8; ++c)
            aq[mt][c] = *(const half8*)(qf + ((size_t)((qb0 >> 4) + mt) * 8 + c) * 512 + lane * 8);

    unsigned best[16];
#pragma unroll
    for (int i = 0; i < 16; ++i) best[i] = 0xFFFFFFFFu;

    const short* bslice = vf + (size_t)sg0 * 8 * 512;   // slice base; g-tile = 8KB contiguous
    const float* vp     = vsqb + sg0 * 16 + tx;

    // stage g-tile (8KB) into buf: 8 x 1KB segments, 2 per wave
    auto stage = [&](short* buf, int g) {
        const short* gsrc = bslice + (size_t)g * 4096;
#pragma unroll
        for (int i = 0; i < 2; ++i) {
            const int seg = w * 2 + i;                   // wave-uniform
            gload_lds16(gsrc + seg * 512 + lane * 8, buf + seg * 512);
        }
    };

    auto compute = [&](const short* buf, int g) {
        const float vsqr = vp[(size_t)g * 16];
        f32x4 acc[4];
#pragma unroll
        for (int i = 0; i < 4; ++i) acc[i] = (f32x4){0.f, 0.f, 0.f, 0.f};
#pragma unroll
        for (int c = 0; c < 8; ++c) {
            const half8 bfr = *(const half8*)(buf + c * 512 + lane * 8);  // linear, no conflicts
#pragma unroll
            for (int mt = 0; mt < 4; ++mt)
                acc[mt] = __builtin_amdgcn_mfma_f32_16x16x32_f16(aq[mt][c], bfr, acc[mt], 0, 0, 0);
        }
#pragma unroll
        for (int mt = 0; mt < 4; ++mt)
#pragma unroll
            for (int r = 0; r < 4; ++r) {
                const float sc = fmaf(-2.f, acc[mt][r], vsqr);
                const unsigned key = (__float_as_uint(sc) & 0xFFFFFFC0u) | (unsigned)g;
                const int sl = mt * 4 + r;
                best[sl] = key < best[sl] ? key : best[sl];
            }
    };

    stage(bt[0], 0);
    __syncthreads();                        // drains vmcnt(0): buf0 ready

    for (int g = 0; g < SLICE_G; g += 2) {
        stage(bt[1], g + 1);                // prefetch next tile (async, no VGPR dest)
        compute(bt[0], g);
        __syncthreads();                    // tile g+1 landed; all reads of bt[0] done
        if (g + 2 < SLICE_G) stage(bt[0], g + 2);
        compute(bt[1], g + 1);
        __syncthreads();
    }

    // Epilogue: per slot, min across 16 tx lanes; recover (g, tx); top-2 insert.
#pragma unroll
    for (int mt = 0; mt < 4; ++mt)
#pragma unroll
        for (int r = 0; r < 4; ++r) {
            const int sl = mt * 4 + r;
            unsigned k = best[sl];
#pragma unroll
            for (int off = 8; off; off >>= 1) {
                const unsigned o = (unsigned)__shfl_xor((int)k, off, 16);
                k = o < k ? o : k;
            }
            const ull bal = __ballot(best[sl] == k);
            const unsigned grp = (unsigned)((bal >> (quad * 16)) & 0xFFFFull);
            const int wtx = __ffs((int)grp) - 1;
            const unsigned n = (unsigned)((sg0 + (int)(k & 63u)) * 16 + wtx);
            if (tx == 0) {
                const int row = qb0 + mt * 16 + quad * 4 + r;
                const ull key64 = ((ull)k << 32) | n;
                const ull old = atomicMin(&keys1[row], key64);
                const ull loser = (key64 < old) ? old : key64;
                if (loser != ~0ull) atomicMin(&keys2[row], loser);
            }
        }
}

// ---------------- Kernel C: exact fp32 rescore of approx top-2 ----------------
__global__ __launch_bounds__(256) void rescore_kernel(const float* __restrict__ q,
                                                      const float* __restrict__ v,
                                                      const ull* __restrict__ keys1,
                                                      const ull* __restrict__ keys2,
                                                      int* __restrict__ out) {
    const int qi   = blockIdx.x * 4 + (threadIdx.x >> 6);
    const int lane = threadIdx.x & 63;
    const float4 qv = *(const float4*)(q + (size_t)qi * D + lane * 4);
    ull best = ~0ull;
    ull cand[2];
    cand[0] = keys1[qi];
    cand[1] = keys2[qi];
#pragma unroll
    for (int c = 0; c < 2; ++c) {
        if (cand[c] == ~0ull) continue;
        const unsigned idx = (unsigned)cand[c];
        const float4 vv = *(const float4*)(v + (size_t)idx * D + lane * 4);
        float s1 = vv.x * vv.x + vv.y * vv.y + vv.z * vv.z + vv.w * vv.w;   // ||v||^2
        float s2 = qv.x * vv.x + qv.y * vv.y + qv.z * vv.z + qv.w * vv.w;   // q.v
#pragma unroll
        for (int off = 32; off; off >>= 1) {
            s1 += __shfl_xor(s1, off, 64);
            s2 += __shfl_xor(s2, off, 64);
        }
        const float dist = fmaf(-2.0f, s2, s1);   // exact fp32 (sans ||q||^2)
        const ull key = pack_key(dist, idx);
        best = best < key ? best : key;
    }
    if (lane == 0) out[qi] = (int)(unsigned)(best & 0xFFFFFFFFull);
}

extern "C" void kernel_launch(void* const* d_in, const int* in_sizes, int n_in,
                              void* d_out, int out_size, void* d_ws, size_t ws_size,
                              hipStream_t stream) {
    const float* q = (const float*)d_in[0];
    const float* v = (const float*)d_in[1];
    int* out = (int*)d_out;

    char* ws = (char*)d_ws;
    float* vsqb = (float*)ws;                ws += (size_t)N * sizeof(float);
    ull* keys1 = (ull*)ws;                   ws += (size_t)2 * M * sizeof(ull);
    ull* keys2 = keys1 + M;
    short* qf = (short*)ws;                  ws += (size_t)M * D * 2;
    short* vf = (short*)ws;                  // 64 MB frag-linear

    convert_fused<<<N / 16 + M / 16, 256, 0, stream>>>(v, q, vf, qf, vsqb, keys1);

    dist_argmin_reg<<<(M / 256) * NSLICE, 256, 0, stream>>>(qf, vf, vsqb, keys1, keys2);

    rescore_kernel<<<M / 4, 256, 0, stream>>>(q, v, keys1, keys2, out);
}